// Round 1
// baseline (46.445 us; speedup 1.0000x reference)
//
#include <hip/hip_runtime.h>

// SugenoFuzzyIntegral — mathematical simplification:
//   g_1 = s_1 (scan starts at 0), and min(s_i,g_i) <= s_i <= s_1 for all i,
//   with equality at i=1. So  integral = max_i min(s_i,g_i) = s_1 =
//   clip(max(mu_row),0,1)  for ANY lambda — sort + scan + lambda are dead.
//   out[b] = clip(rowmax,0,1) * mu[b, tc[b]] / (rowmax + 1e-8)

#define EPS 1e-8f

__global__ __launch_bounds__(256) void sugeno_rowmax_kernel(
    const float* __restrict__ mu,
    const int*   __restrict__ tc,
    float*       __restrict__ out,
    int B, int C)
{
    const int wave = threadIdx.x >> 6;          // 4 waves per block
    const int lane = threadIdx.x & 63;
    const int row  = (blockIdx.x << 2) + wave;  // one wave per row
    if (row >= B) return;

    const size_t row_off = (size_t)row * (size_t)C;
    const float4* rowp = reinterpret_cast<const float4*>(mu + row_off);
    const int nvec = C >> 2;                    // C=1000 -> 250 float4s (16B aligned: 4000%16==0)

    float m = -INFINITY;
    #pragma unroll 4
    for (int k = lane; k < nvec; k += 64) {
        float4 v = rowp[k];
        m = fmaxf(m, fmaxf(fmaxf(v.x, v.y), fmaxf(v.z, v.w)));
    }
    // scalar tail (C % 4 != 0) — not hit for C=1000, kept for generality
    for (int c = (nvec << 2) + lane; c < C; c += 64)
        m = fmaxf(m, mu[row_off + c]);

    // 64-lane butterfly max reduce
    #pragma unroll
    for (int off = 32; off > 0; off >>= 1)
        m = fmaxf(m, __shfl_xor(m, off, 64));

    if (lane == 0) {
        const int t = tc[row];
        const float tv = mu[row_off + (size_t)t];   // L1-resident: row just read
        const float s1 = fminf(fmaxf(m, 0.0f), 1.0f);
        out[row] = s1 * (tv / (m + EPS));
    }
}

extern "C" void kernel_launch(void* const* d_in, const int* in_sizes, int n_in,
                              void* d_out, int out_size, void* d_ws, size_t ws_size,
                              hipStream_t stream)
{
    const float* mu = (const float*)d_in[0];
    const int*   tc = (const int*)d_in[1];
    // d_in[2] = log_lambda: provably irrelevant to the output (see header note).
    float* out = (float*)d_out;

    const int B = in_sizes[1];                  // 65536 rows (== target_class count)
    const int C = in_sizes[0] / B;              // 1000 classes

    const int rows_per_block = 4;               // 4 waves x 64 lanes
    const int grid = (B + rows_per_block - 1) / rows_per_block;
    sugeno_rowmax_kernel<<<grid, 256, 0, stream>>>(mu, tc, out, B, C);
}

// Round 2
// 42.627 us; speedup vs baseline: 1.0896x; 1.0896x over previous
//
#include <hip/hip_runtime.h>

// SugenoFuzzyIntegral — math reduction (verified R1, absmax 0.0):
//   integral = clip(max(mu_row),0,1) for any lambda, so
//   out[b] = clip(rowmax,0,1) * mu[b,tc[b]] / (rowmax + 1e-8)
//
// R2 structure: one wave per row, 4 unconditional global_load_dwordx4
// (no loop, no trip-count divergence), tc[] scalar-loaded up front,
// target value extracted in-register via __shfl (no dependent re-read).

#define EPS 1e-8f

__global__ __launch_bounds__(256) void sugeno_rowmax_c1000(
    const float* __restrict__ mu,
    const int*   __restrict__ tc,
    float*       __restrict__ out,
    int B)
{
    constexpr int C = 1000;
    constexpr int NVEC = C / 4;                 // 250 float4s per row
    const int wave = threadIdx.x >> 6;
    const int lane = threadIdx.x & 63;
    const int row  = (blockIdx.x << 2) + wave;  // one wave per row
    if (row >= B) return;

    // Wave-uniform target index: issued first, overlaps the row stream.
    const int t = tc[row];

    const float4* rowp = reinterpret_cast<const float4*>(mu + (size_t)row * C);

    // 4 independent, unconditional 16B loads per lane (250 = 3*64 + 58;
    // lanes 58..63 clamp to vec 249 — duplicate element is harmless for max).
    const int k3t = lane + 192;
    const int k3  = k3t < NVEC ? k3t : NVEC - 1;
    float4 v0 = rowp[lane];
    float4 v1 = rowp[lane + 64];
    float4 v2 = rowp[lane + 128];
    float4 v3 = rowp[k3];

    float m0 = fmaxf(fmaxf(v0.x, v0.y), fmaxf(v0.z, v0.w));
    float m1 = fmaxf(fmaxf(v1.x, v1.y), fmaxf(v1.z, v1.w));
    float m2 = fmaxf(fmaxf(v2.x, v2.y), fmaxf(v2.z, v2.w));
    float m3 = fmaxf(fmaxf(v3.x, v3.y), fmaxf(v3.z, v3.w));
    float m  = fmaxf(fmaxf(m0, m1), fmaxf(m2, m3));

    #pragma unroll
    for (int off = 32; off > 0; off >>= 1)
        m = fmaxf(m, __shfl_xor(m, off, 64));

    // In-register target extraction: element t lives in load (t>>2)>>6 of
    // lane (t>>2)&63. All selects are wave-uniform (t is uniform).
    const int kt    = t >> 2;
    const int it    = kt >> 6;
    const int owner = kt & 63;
    float4 sel = (it == 0) ? v0 : (it == 1) ? v1 : (it == 2) ? v2 : v3;
    const int comp = t & 3;
    float val = (comp == 0) ? sel.x : (comp == 1) ? sel.y
              : (comp == 2) ? sel.z : sel.w;
    const float tv = __shfl(val, owner, 64);

    if (lane == 0) {
        const float s1 = fminf(fmaxf(m, 0.0f), 1.0f);
        out[row] = s1 * (tv / (m + EPS));
    }
}

// Generic fallback (any C) — same algorithm, looped.
__global__ __launch_bounds__(256) void sugeno_rowmax_generic(
    const float* __restrict__ mu,
    const int*   __restrict__ tc,
    float*       __restrict__ out,
    int B, int C)
{
    const int wave = threadIdx.x >> 6;
    const int lane = threadIdx.x & 63;
    const int row  = (blockIdx.x << 2) + wave;
    if (row >= B) return;

    const int t = tc[row];
    const size_t row_off = (size_t)row * (size_t)C;

    float m = -INFINITY;
    for (int c = lane; c < C; c += 64)
        m = fmaxf(m, mu[row_off + c]);
    #pragma unroll
    for (int off = 32; off > 0; off >>= 1)
        m = fmaxf(m, __shfl_xor(m, off, 64));

    if (lane == 0) {
        const float tv = mu[row_off + (size_t)t];
        const float s1 = fminf(fmaxf(m, 0.0f), 1.0f);
        out[row] = s1 * (tv / (m + EPS));
    }
}

extern "C" void kernel_launch(void* const* d_in, const int* in_sizes, int n_in,
                              void* d_out, int out_size, void* d_ws, size_t ws_size,
                              hipStream_t stream)
{
    const float* mu = (const float*)d_in[0];
    const int*   tc = (const int*)d_in[1];
    // d_in[2] = log_lambda: provably irrelevant (see header).
    float* out = (float*)d_out;

    const int B = in_sizes[1];
    const int C = in_sizes[0] / B;

    const int grid = (B + 3) / 4;               // 4 waves (rows) per block
    if (C == 1000)
        sugeno_rowmax_c1000<<<grid, 256, 0, stream>>>(mu, tc, out, B);
    else
        sugeno_rowmax_generic<<<grid, 256, 0, stream>>>(mu, tc, out, B, C);
}

// Round 3
// 42.114 us; speedup vs baseline: 1.1029x; 1.0122x over previous
//
#include <hip/hip_runtime.h>

// SugenoFuzzyIntegral — math reduction (verified R1/R2, absmax 0.0):
//   integral = clip(max(mu_row),0,1) for any lambda  =>
//   out[b] = clip(rowmax,0,1) * mu[b,tc[b]] / (rowmax + 1e-8)
//
// R3: two rows per wave (8 outstanding dwordx4 -> 2x MLP, half the waves,
// reduce chains interleaved), nontemporal loads (pure stream, no reuse),
// paired float2 store from lane 0.

#define EPS 1e-8f

typedef float f32x4 __attribute__((ext_vector_type(4)));

__device__ __forceinline__ float vmax4(f32x4 v) {
    return fmaxf(fmaxf(v.x, v.y), fmaxf(v.z, v.w));
}
__device__ __forceinline__ float pick(f32x4 v, int comp) {
    return (comp == 0) ? v.x : (comp == 1) ? v.y : (comp == 2) ? v.z : v.w;
}

__global__ __launch_bounds__(256) void sugeno_rowmax_c1000_x2(
    const float* __restrict__ mu,
    const int*   __restrict__ tc,
    float*       __restrict__ out,
    int B)
{
    constexpr int C = 1000;
    constexpr int NVEC = C / 4;                   // 250
    const int wave = threadIdx.x >> 6;
    const int lane = threadIdx.x & 63;
    const int rp   = (((blockIdx.x << 2) + wave) << 1);   // even row pair base
    if (rp >= B) return;

    // Wave-uniform target indices (scalar loads, overlap the stream).
    const int t0 = tc[rp];
    const int t1 = tc[rp + 1];

    const f32x4* r0 = reinterpret_cast<const f32x4*>(mu + (size_t)rp * C);
    const f32x4* r1 = reinterpret_cast<const f32x4*>(mu + (size_t)(rp + 1) * C);

    // 250 = 3*64 + 58; lanes 58..63 clamp to vec 249 (dup harmless for max).
    const int k3 = (lane + 192 < NVEC) ? lane + 192 : NVEC - 1;

    // 8 independent nontemporal 16B loads in flight before any use.
    f32x4 a0 = __builtin_nontemporal_load(r0 + lane);
    f32x4 a1 = __builtin_nontemporal_load(r0 + lane + 64);
    f32x4 a2 = __builtin_nontemporal_load(r0 + lane + 128);
    f32x4 a3 = __builtin_nontemporal_load(r0 + k3);
    f32x4 b0 = __builtin_nontemporal_load(r1 + lane);
    f32x4 b1 = __builtin_nontemporal_load(r1 + lane + 64);
    f32x4 b2 = __builtin_nontemporal_load(r1 + lane + 128);
    f32x4 b3 = __builtin_nontemporal_load(r1 + k3);

    float m = fmaxf(fmaxf(vmax4(a0), vmax4(a1)), fmaxf(vmax4(a2), vmax4(a3)));
    float n = fmaxf(fmaxf(vmax4(b0), vmax4(b1)), fmaxf(vmax4(b2), vmax4(b3)));

    // Two butterfly reduces, interleaved for ILP.
    #pragma unroll
    for (int off = 32; off > 0; off >>= 1) {
        m = fmaxf(m, __shfl_xor(m, off, 64));
        n = fmaxf(n, __shfl_xor(n, off, 64));
    }

    // In-register target extraction (t0/t1 wave-uniform).
    const int kt0 = t0 >> 2, it0 = kt0 >> 6, own0 = kt0 & 63;
    const int kt1 = t1 >> 2, it1 = kt1 >> 6, own1 = kt1 & 63;
    f32x4 sa = (it0 == 0) ? a0 : (it0 == 1) ? a1 : (it0 == 2) ? a2 : a3;
    f32x4 sb = (it1 == 0) ? b0 : (it1 == 1) ? b1 : (it1 == 2) ? b2 : b3;
    const float tv0 = __shfl(pick(sa, t0 & 3), own0, 64);
    const float tv1 = __shfl(pick(sb, t1 & 3), own1, 64);

    if (lane == 0) {
        const float s0 = fminf(fmaxf(m, 0.0f), 1.0f);
        const float s1 = fminf(fmaxf(n, 0.0f), 1.0f);
        float2 o = make_float2(s0 * (tv0 / (m + EPS)),
                               s1 * (tv1 / (n + EPS)));
        *reinterpret_cast<float2*>(out + rp) = o;   // rp even -> 8B aligned
    }
}

// Generic fallback (any C / odd B) — same algorithm, looped, 1 row/wave.
__global__ __launch_bounds__(256) void sugeno_rowmax_generic(
    const float* __restrict__ mu,
    const int*   __restrict__ tc,
    float*       __restrict__ out,
    int B, int C)
{
    const int wave = threadIdx.x >> 6;
    const int lane = threadIdx.x & 63;
    const int row  = (blockIdx.x << 2) + wave;
    if (row >= B) return;

    const int t = tc[row];
    const size_t row_off = (size_t)row * (size_t)C;

    float m = -INFINITY;
    for (int c = lane; c < C; c += 64)
        m = fmaxf(m, mu[row_off + c]);
    #pragma unroll
    for (int off = 32; off > 0; off >>= 1)
        m = fmaxf(m, __shfl_xor(m, off, 64));

    if (lane == 0) {
        const float tv = mu[row_off + (size_t)t];
        const float s1 = fminf(fmaxf(m, 0.0f), 1.0f);
        out[row] = s1 * (tv / (m + EPS));
    }
}

extern "C" void kernel_launch(void* const* d_in, const int* in_sizes, int n_in,
                              void* d_out, int out_size, void* d_ws, size_t ws_size,
                              hipStream_t stream)
{
    const float* mu = (const float*)d_in[0];
    const int*   tc = (const int*)d_in[1];
    // d_in[2] = log_lambda: provably irrelevant (see header).
    float* out = (float*)d_out;

    const int B = in_sizes[1];
    const int C = in_sizes[0] / B;

    if (C == 1000 && (B & 1) == 0) {
        const int pairs = B >> 1;                 // waves needed
        const int grid  = (pairs + 3) / 4;        // 4 waves per block
        sugeno_rowmax_c1000_x2<<<grid, 256, 0, stream>>>(mu, tc, out, B);
    } else {
        const int grid = (B + 3) / 4;
        sugeno_rowmax_generic<<<grid, 256, 0, stream>>>(mu, tc, out, B, C);
    }
}